// Round 2
// baseline (145.291 us; speedup 1.0000x reference)
//
#include <hip/hip_runtime.h>
#include <hip/hip_cooperative_groups.h>

namespace cg = cooperative_groups;

// MIOSTONE tree-MLP, B=32, LEAVES=4096, H=32, K=8, D=4, OUT=2.
// Single cooperative kernel: 256 blocks x 512 threads, 2 grid syncs.
// Stage 1 (all blocks): layer 3 (leaves) + layer 2 per depth-2 subtree.
// Stage 2 (blocks 0..31): layer 1 with register-prefetched weights +
//                         layer-0 partial sums (deterministic slots).
// Stage 3 (block 0): bias+gate for layer 0, BatchNorm, output matmul.

__device__ __forceinline__ float dot4(float4 a, float4 b, float acc) {
    acc = fmaf(a.x, b.x, acc);
    acc = fmaf(a.y, b.y, acc);
    acc = fmaf(a.z, b.z, acc);
    acc = fmaf(a.w, b.w, acc);
    return acc;
}

__device__ __forceinline__ float4 ld4(const float* p) {
    return *(const float4*)p;
}

__global__ __launch_bounds__(512)
void fused_tree(const float* __restrict__ x,
                const float* __restrict__ Wm3, const float* __restrict__ bm3,
                const float* __restrict__ Wl3, const float* __restrict__ bl3,
                const float* __restrict__ Wm2, const float* __restrict__ bm2,
                const float* __restrict__ Wl2, const float* __restrict__ bl2,
                const float* __restrict__ Wm1, const float* __restrict__ bm1,
                const float* __restrict__ Wl1, const float* __restrict__ bl1,
                const float* __restrict__ Wm0, const float* __restrict__ bm0,
                const float* __restrict__ Wl0, const float* __restrict__ bl0,
                const float* __restrict__ gate_p,
                const float* __restrict__ bn_gamma, const float* __restrict__ bn_beta,
                const float* __restrict__ Wout, const float* __restrict__ bout,
                float* __restrict__ X2, float* __restrict__ XL2,
                float* __restrict__ Pm, float* __restrict__ Pl,
                float* __restrict__ out)
{
    cg::grid_group grid = cg::this_grid();
    const int blk = blockIdx.x;   // 0..255
    const int tid = threadIdx.x;  // 0..511
    const float g = gate_p[0], gi = 1.0f - g;

    // ---- LDS (static, ~34 KB total) ----
    __shared__ __align__(16) float xs[8][64];     // stage-1 input slice
    __shared__ __align__(16) float x3[8][260];    // gated layer-3 out (pad 260)
    __shared__ __align__(16) float xl3[8][260];   // linear-chain layer-3 out
    __shared__ float x1s[8][33];                  // stage-2 gated layer-1 out
    __shared__ float xl1s[8][33];                 // stage-2 linear layer-1 out
    __shared__ float wm0s[32][33];                // stage-2 Wm0 slice
    __shared__ float wl0s[32][33];                // stage-2 Wl0 slice
    __shared__ float x0[32][33];                  // stage-3 gated layer-0 out
    __shared__ float bnm[32], bna[32];            // BN scale/shift
    __shared__ float pW[64], pbo[2], pg[32], pb[32], pbm0[32], pbl0[32];

    // ================= entry prefetches (latency hides under stage 1) ======
    float4 wmv0{}, wmv1{}, wmv2{}, wmv3{};        // layer-1 mlp weights (16 f)
    float4 wlv0{}, wlv1{}, wlv2{}, wlv3{};        // layer-1 linear weights
    float bmv = 0.0f, blv = 0.0f;
    if (blk < 32) {
        const int j1 = blk >> 2;
        const int t = tid >> 4, seg = tid & 15;
        const int row = j1 * 32 + t;
        const float* wr = Wm1 + row * 2048 + j1 * 256 + seg * 16;
        const float* lr = Wl1 + row * 2048 + j1 * 256 + seg * 16;
        wmv0 = ld4(wr);      wmv1 = ld4(wr + 4);
        wmv2 = ld4(wr + 8);  wmv3 = ld4(wr + 12);
        wlv0 = ld4(lr);      wlv1 = ld4(lr + 4);
        wlv2 = ld4(lr + 8);  wlv3 = ld4(lr + 12);
        bmv = bm1[row]; blv = bl1[row];
        // Wm0/Wl0 column slice for this j1 -> LDS
        int i0 = tid, i1 = tid + 512;
        wm0s[i0 >> 5][i0 & 31] = Wm0[(i0 >> 5) * 256 + j1 * 32 + (i0 & 31)];
        wm0s[i1 >> 5][i1 & 31] = Wm0[(i1 >> 5) * 256 + j1 * 32 + (i1 & 31)];
        wl0s[i0 >> 5][i0 & 31] = Wl0[(i0 >> 5) * 256 + j1 * 32 + (i0 & 31)];
        wl0s[i1 >> 5][i1 & 31] = Wl0[(i1 >> 5) * 256 + j1 * 32 + (i1 & 31)];
    }
    if (blk == 0) {
        if (tid < 64) pW[tid] = Wout[tid];
        if (tid < 32) {
            pg[tid]   = bn_gamma[tid];
            pb[tid]   = bn_beta[tid];
            pbm0[tid] = bm0[tid];
            pbl0[tid] = bl0[tid];
        }
        if (tid < 2) pbo[tid] = bout[tid];
    }

    // ================= stage 1: layers 3 & 2 ===============================
    const int j2 = blk & 63, rg = blk >> 6;

    {   // load x slice: rows rg*8..+7, cols j2*64..+63 (512 elems, 1/thread)
        int b = tid >> 6, c = tid & 63;
        xs[b][c] = x[(rg * 8 + b) * 4096 + j2 * 64 + c];
    }
    __syncthreads();

    {   // layer 3: thread = (col 0..255, half h) -> 4 batch rows each
        const int col = tid & 255, h = tid >> 8;
        const int l = col >> 5, t3 = col & 31;
        const int j3 = j2 * 8 + l;
        const int row = j3 * 32 + t3;
        const float* wmr = Wm3 + (size_t)row * 4096 + j3 * 8;
        const float* wlr = Wl3 + (size_t)row * 4096 + j3 * 8;
        const float4 wma = ld4(wmr), wmb = ld4(wmr + 4);
        const float4 wla = ld4(wlr), wlb = ld4(wlr + 4);
        const float bm = bm3[row], bl = bl3[row];
#pragma unroll
        for (int i = 0; i < 4; ++i) {
            const int b = h * 4 + i;
            const float4 xa = ld4(&xs[b][l * 8]);
            const float4 xb = ld4(&xs[b][l * 8 + 4]);
            float am = dot4(xa, wma, bm); am = dot4(xb, wmb, am);
            float al = dot4(xa, wla, bl); al = dot4(xb, wlb, al);
            float hh = fmaxf(am, 0.0f);
            x3[b][col]  = fmaf(g, hh, gi * al);
            xl3[b][col] = al;
        }
    }
    __syncthreads();

    {   // layer 2: thread = (t 0..31, b 0..7, h 0..1) half-dot + shfl reduce
        const int t = tid >> 4, b = (tid >> 1) & 7, h = tid & 1;
        const int row = j2 * 32 + t;
        const float* wmr = Wm2 + (size_t)row * 16384 + j2 * 256 + h * 128;
        const float* wlr = Wl2 + (size_t)row * 16384 + j2 * 256 + h * 128;
        float pm = 0.0f, pl = 0.0f;
#pragma unroll 8
        for (int c = 0; c < 128; c += 4) {
            pm = dot4(ld4(&x3 [b][h * 128 + c]), ld4(wmr + c), pm);
            pl = dot4(ld4(&xl3[b][h * 128 + c]), ld4(wlr + c), pl);
        }
        pm += __shfl_xor(pm, 1);
        pl += __shfl_xor(pl, 1);
        const float am = pm + bm2[row], al = pl + bl2[row];
        const float xg = fmaf(g, fmaxf(am, 0.0f), gi * al);
        const int gb = rg * 8 + b;
        if (h == 0) X2 [gb * 2048 + j2 * 32 + t] = xg;
        else        XL2[gb * 2048 + j2 * 32 + t] = al;
    }
    __threadfence();
    grid.sync();

    // ================= stage 2: layer 1 + layer-0 partials =================
    if (blk < 32) {
        const int j1 = blk >> 2, rg2 = blk & 3;
        const int t = tid >> 4, seg = tid & 15;
        const int xbase = j1 * 256 + seg * 16;
#pragma unroll
        for (int b = 0; b < 8; ++b) {
            const int gb = rg2 * 8 + b;
            const float* xp  = X2  + gb * 2048 + xbase;
            const float* xlp = XL2 + gb * 2048 + xbase;
            float pm = dot4(ld4(xp),      wmv0, 0.0f);
            pm       = dot4(ld4(xp + 4),  wmv1, pm);
            pm       = dot4(ld4(xp + 8),  wmv2, pm);
            pm       = dot4(ld4(xp + 12), wmv3, pm);
            float pl = dot4(ld4(xlp),      wlv0, 0.0f);
            pl       = dot4(ld4(xlp + 4),  wlv1, pl);
            pl       = dot4(ld4(xlp + 8),  wlv2, pl);
            pl       = dot4(ld4(xlp + 12), wlv3, pl);
#pragma unroll
            for (int s = 1; s < 16; s <<= 1) {
                pm += __shfl_xor(pm, s);
                pl += __shfl_xor(pl, s);
            }
            if (seg == 0) {
                const float am = pm + bmv, al = pl + blv;
                x1s [b][t] = fmaf(g, fmaxf(am, 0.0f), gi * al);
                xl1s[b][t] = al;
            }
        }
        __syncthreads();
        // layer-0 partials over this block's 32 columns (deterministic slots)
        if (tid < 256) {
            const int b = tid >> 5, o = tid & 31;
            float pm0 = 0.0f, pl0 = 0.0f;
#pragma unroll 8
            for (int t0 = 0; t0 < 32; ++t0) {
                pm0 = fmaf(x1s [b][t0], wm0s[o][t0], pm0);
                pl0 = fmaf(xl1s[b][t0], wl0s[o][t0], pl0);
            }
            const int gb = rg2 * 8 + b;
            Pm[j1 * 1024 + gb * 32 + o] = pm0;
            Pl[j1 * 1024 + gb * 32 + o] = pl0;
        }
        __threadfence();
    }
    grid.sync();

    // ================= stage 3: bias+gate, BatchNorm, output ===============
    if (blk == 0) {
        {
            const int o = tid & 31, bb = tid >> 5;  // bb 0..15
#pragma unroll
            for (int r = bb; r < 32; r += 16) {
                float am = pbm0[o], al = pbl0[o];
#pragma unroll
                for (int j = 0; j < 8; ++j) {
                    am += Pm[j * 1024 + r * 32 + o];
                    al += Pl[j * 1024 + r * 32 + o];
                }
                x0[r][o] = fmaf(g, fmaxf(am, 0.0f), gi * al);
            }
        }
        __syncthreads();
        if (tid < 32) {
            float s = 0.0f, s2 = 0.0f;
#pragma unroll
            for (int r = 0; r < 32; ++r) {
                float v = x0[r][tid];
                s += v;
                s2 = fmaf(v, v, s2);
            }
            const float mu  = s * (1.0f / 32.0f);
            const float var = s2 * (1.0f / 32.0f) - mu * mu;
            const float m = pg[tid] * rsqrtf(var + 1e-5f);
            bnm[tid] = m;
            bna[tid] = fmaf(-mu, m, pb[tid]);
        }
        __syncthreads();
        if (tid < 64) {
            const int b = tid >> 1, oo = tid & 1;
            float acc = pbo[oo];
#pragma unroll
            for (int t0 = 0; t0 < 32; ++t0) {
                const float xn = fmaf(x0[b][t0], bnm[t0], bna[t0]);
                acc = fmaf(xn, pW[oo * 32 + t0], acc);
            }
            out[b * 2 + oo] = acc;
        }
    }
}

extern "C" void kernel_launch(void* const* d_in, const int* in_sizes, int n_in,
                              void* d_out, int out_size, void* d_ws, size_t ws_size,
                              hipStream_t stream)
{
    const float* x    = (const float*)d_in[0];
    const float* Wm3  = (const float*)d_in[1];
    const float* bm3  = (const float*)d_in[2];
    const float* Wl3  = (const float*)d_in[3];
    const float* bl3  = (const float*)d_in[4];
    const float* Wm2  = (const float*)d_in[5];
    const float* bm2  = (const float*)d_in[6];
    const float* Wl2  = (const float*)d_in[7];
    const float* bl2  = (const float*)d_in[8];
    const float* Wm1  = (const float*)d_in[9];
    const float* bm1  = (const float*)d_in[10];
    const float* Wl1  = (const float*)d_in[11];
    const float* bl1  = (const float*)d_in[12];
    const float* Wm0  = (const float*)d_in[13];
    const float* bm0  = (const float*)d_in[14];
    const float* Wl0  = (const float*)d_in[15];
    const float* bl0  = (const float*)d_in[16];
    const float* gate = (const float*)d_in[17];
    const float* bn_g = (const float*)d_in[18];
    const float* bn_b = (const float*)d_in[19];
    const float* Wout = (const float*)d_in[20];
    const float* bout = (const float*)d_in[21];
    float* outp = (float*)d_out;

    float* ws  = (float*)d_ws;
    float* X2  = ws;             // 65536 floats
    float* XL2 = ws + 65536;     // 65536
    float* Pm  = ws + 131072;    // 8192
    float* Pl  = ws + 139264;    // 8192

    void* args[] = {
        (void*)&x,
        (void*)&Wm3, (void*)&bm3, (void*)&Wl3, (void*)&bl3,
        (void*)&Wm2, (void*)&bm2, (void*)&Wl2, (void*)&bl2,
        (void*)&Wm1, (void*)&bm1, (void*)&Wl1, (void*)&bl1,
        (void*)&Wm0, (void*)&bm0, (void*)&Wl0, (void*)&bl0,
        (void*)&gate, (void*)&bn_g, (void*)&bn_b, (void*)&Wout, (void*)&bout,
        (void*)&X2, (void*)&XL2, (void*)&Pm, (void*)&Pl, (void*)&outp
    };
    hipLaunchCooperativeKernel((void*)fused_tree, dim3(256), dim3(512),
                               args, 0, stream);
}

// Round 3
// 23.663 us; speedup vs baseline: 6.1400x; 6.1400x over previous
//
#include <hip/hip_runtime.h>

// MIOSTONE tree-MLP, B=32, LEAVES=4096, H=32, K=8, D=4, OUT=2.
// Two kernels:
//  K1 (256 blocks x 512): layer 3 (leaves) + layer 2 per depth-2 subtree,
//     weights async-staged to LDS at entry. Also resets the tail counter.
//  K2 (32 blocks x 512): layer 1 (async-staged weights) + layer-0 partial
//     sums; the last-finishing block reduces partials + BatchNorm + output.

__device__ __forceinline__ float dot4(float4 a, float4 b, float acc) {
    acc = fmaf(a.x, b.x, acc);
    acc = fmaf(a.y, b.y, acc);
    acc = fmaf(a.z, b.z, acc);
    acc = fmaf(a.w, b.w, acc);
    return acc;
}
__device__ __forceinline__ float4 ld4(const float* p) { return *(const float4*)p; }

typedef const __attribute__((address_space(1))) void* gas_t;
typedef __attribute__((address_space(3))) void* las_t;

// async global->LDS, 16B per lane (one wave call moves 1024B)
__device__ __forceinline__ void gl_lds16(const float* g, float* l) {
    __builtin_amdgcn_global_load_lds((gas_t)g, (las_t)l, 16, 0, 0);
}
// async global->LDS, 4B per lane (one wave call moves 256B)
__device__ __forceinline__ void gl_lds4(const float* g, float* l) {
    __builtin_amdgcn_global_load_lds((gas_t)g, (las_t)l, 4, 0, 0);
}

// ============================ Kernel 1 =====================================
__global__ __launch_bounds__(512)
void k_subtree(const float* __restrict__ x,
               const float* __restrict__ Wm3, const float* __restrict__ bm3,
               const float* __restrict__ Wl3, const float* __restrict__ bl3,
               const float* __restrict__ Wm2, const float* __restrict__ bm2,
               const float* __restrict__ Wl2, const float* __restrict__ bl2,
               const float* __restrict__ gate_p,
               float* __restrict__ X2, float* __restrict__ XL2,
               int* __restrict__ cnt)
{
    const int blk = blockIdx.x;          // rg*64 + j2  (same-j2 -> same XCD)
    const int j2 = blk & 63, rg = blk >> 6;
    const int tid = threadIdx.x;         // 0..511
    const int wv = tid >> 6, ln = tid & 63;

    if (blk == 0 && tid == 0) *cnt = 0;  // reset tail counter for kernel 2

    __shared__ __align__(16) float xs[8][64];       // input slice
    __shared__ __align__(16) float w2[2][32][260];  // layer-2 weight panel
    __shared__ __align__(16) float x3[8][260];      // gated layer-3 out
    __shared__ __align__(16) float xl3[8][260];     // linear layer-3 out

    // ---- async stage: x row + 64 weight rows (8 per wave) ----
    gl_lds4(x + (rg * 8 + wv) * 4096 + j2 * 64 + ln, &xs[wv][0]);
#pragma unroll
    for (int i = 0; i < 8; ++i) {
        const int q = wv * 8 + i;        // 0..63
        const int m = q >> 5, r = q & 31;
        const float* src = (m ? Wl2 : Wm2)
                         + (size_t)(j2 * 32 + r) * 16384 + j2 * 256 + ln * 4;
        gl_lds16(src, &w2[m][r][0]);
    }

    // ---- layer-3 weights -> registers (issued before the barrier) ----
    const int col = tid & 255, h = tid >> 8;
    const int l3 = col >> 5, t3 = col & 31;
    const int j3 = j2 * 8 + l3;
    const int row3 = j3 * 32 + t3;
    const float* wmr = Wm3 + (size_t)row3 * 4096 + j3 * 8;
    const float* wlr = Wl3 + (size_t)row3 * 4096 + j3 * 8;
    const float4 wma = ld4(wmr), wmb = ld4(wmr + 4);
    const float4 wla = ld4(wlr), wlb = ld4(wlr + 4);
    const float bm = bm3[row3], bl = bl3[row3];
    const int t2 = tid >> 4;                         // layer-2 out row
    const float bmv2 = bm2[j2 * 32 + t2];
    const float blv2 = bl2[j2 * 32 + t2];
    const float g = gate_p[0], gi = 1.0f - g;

    __syncthreads();   // drains vmcnt: xs + w2 + reg weights all ready

    // ---- layer 3: thread (col, h) computes 4 batch rows ----
#pragma unroll
    for (int i = 0; i < 4; ++i) {
        const int b = h * 4 + i;
        const float4 xa = ld4(&xs[b][l3 * 8]);
        const float4 xb = ld4(&xs[b][l3 * 8 + 4]);
        float am = dot4(xa, wma, bm); am = dot4(xb, wmb, am);
        float al = dot4(xa, wla, bl); al = dot4(xb, wlb, al);
        x3[b][col]  = fmaf(g, fmaxf(am, 0.0f), gi * al);
        xl3[b][col] = al;
    }
    __syncthreads();

    // ---- layer 2: thread (t2, b, hh) half-dot + shfl reduce ----
    {
        const int b = (tid >> 1) & 7, hh = tid & 1;
        const float* wm = &w2[0][t2][hh * 128];
        const float* wl = &w2[1][t2][hh * 128];
        float pm = 0.0f, pl = 0.0f;
#pragma unroll 8
        for (int c = 0; c < 128; c += 4) {
            pm = dot4(ld4(&x3 [b][hh * 128 + c]), ld4(wm + c), pm);
            pl = dot4(ld4(&xl3[b][hh * 128 + c]), ld4(wl + c), pl);
        }
        pm += __shfl_xor(pm, 1);
        pl += __shfl_xor(pl, 1);
        const float am = pm + bmv2, al = pl + blv2;
        const int gb = rg * 8 + b;
        if (hh == 0) X2 [gb * 2048 + j2 * 32 + t2] = fmaf(g, fmaxf(am, 0.0f), gi * al);
        else         XL2[gb * 2048 + j2 * 32 + t2] = al;
    }
}

// ============================ Kernel 2 =====================================
__global__ __launch_bounds__(512)
void k_l1tail(const float* __restrict__ X2, const float* __restrict__ XL2,
              const float* __restrict__ Wm1, const float* __restrict__ bm1,
              const float* __restrict__ Wl1, const float* __restrict__ bl1,
              const float* __restrict__ Wm0, const float* __restrict__ bm0,
              const float* __restrict__ Wl0, const float* __restrict__ bl0,
              const float* __restrict__ gate_p,
              const float* __restrict__ bn_gamma, const float* __restrict__ bn_beta,
              const float* __restrict__ Wout, const float* __restrict__ bout,
              float* __restrict__ Pm, float* __restrict__ Pl,
              int* __restrict__ cnt,
              float* __restrict__ out)
{
    const int blk = blockIdx.x;          // rg*8 + j1 (same-j1 -> same XCD)
    const int j1 = blk & 7, rg = blk >> 3;
    const int tid = threadIdx.x;
    const int wv = tid >> 6, ln = tid & 63;
    const float g = gate_p[0], gi = 1.0f - g;

    __shared__ __align__(16) float w1[2][32][260];   // layer-1 weight panel
    __shared__ __align__(16) float u [8][260];       // X2 slice
    __shared__ __align__(16) float ul[8][260];       // XL2 slice
    __shared__ float wm0s[32][33], wl0s[32][33];     // layer-0 weight slice
    __shared__ float x1s[8][33], xl1s[8][33];
    __shared__ float x0[32][33];
    __shared__ float bnm[32], bna[32];
    __shared__ int is_last;

    // ---- async stage: activations + weight panel ----
    gl_lds16(X2  + (rg * 8 + wv) * 2048 + j1 * 256 + ln * 4, &u [wv][0]);
    gl_lds16(XL2 + (rg * 8 + wv) * 2048 + j1 * 256 + ln * 4, &ul[wv][0]);
#pragma unroll
    for (int i = 0; i < 8; ++i) {
        const int q = wv * 8 + i;
        const int m = q >> 5, r = q & 31;
        const float* src = (m ? Wl1 : Wm1)
                         + (size_t)(j1 * 32 + r) * 2048 + j1 * 256 + ln * 4;
        gl_lds16(src, &w1[m][r][0]);
    }
    // layer-0 weight slice (padded -> manual staging)
    for (int i = tid; i < 1024; i += 512) {
        const int o = i >> 5, t = i & 31;
        wm0s[o][t] = Wm0[o * 256 + j1 * 32 + t];
        wl0s[o][t] = Wl0[o * 256 + j1 * 32 + t];
    }
    const int t1 = tid >> 4;
    const float bmv = bm1[j1 * 32 + t1], blv = bl1[j1 * 32 + t1];

    __syncthreads();

    // ---- layer 1: thread (t1, b, hh) half-dot + shfl reduce ----
    {
        const int b = (tid >> 1) & 7, hh = tid & 1;
        float pm = 0.0f, pl = 0.0f;
#pragma unroll 8
        for (int c = 0; c < 128; c += 4) {
            pm = dot4(ld4(&u [b][hh * 128 + c]), ld4(&w1[0][t1][hh * 128 + c]), pm);
            pl = dot4(ld4(&ul[b][hh * 128 + c]), ld4(&w1[1][t1][hh * 128 + c]), pl);
        }
        pm += __shfl_xor(pm, 1);
        pl += __shfl_xor(pl, 1);
        if (hh == 0) {
            const float am = pm + bmv, al = pl + blv;
            x1s [b][t1] = fmaf(g, fmaxf(am, 0.0f), gi * al);
            xl1s[b][t1] = al;
        }
    }
    __syncthreads();

    // ---- layer-0 partial sums over this block's 32 features ----
    if (tid < 256) {
        const int b = tid >> 5, o = tid & 31;
        float pm0 = 0.0f, pl0 = 0.0f;
#pragma unroll 8
        for (int k = 0; k < 32; ++k) {
            pm0 = fmaf(x1s [b][k], wm0s[o][k], pm0);
            pl0 = fmaf(xl1s[b][k], wl0s[o][k], pl0);
        }
        const int gb = rg * 8 + b;
        Pm[j1 * 1024 + gb * 32 + o] = pm0;
        Pl[j1 * 1024 + gb * 32 + o] = pl0;
    }
    __syncthreads();                       // block's stores drained (vmcnt)

    if (tid == 0) {
        __threadfence();                   // release: writeback to device scope
        const int old = atomicAdd(cnt, 1);
        is_last = (old == 31) ? 1 : 0;
    }
    __syncthreads();
    if (!is_last) return;

    // ================= tail (last block only) ==============================
    if (tid == 0) __threadfence();         // acquire: invalidate stale cache
    __syncthreads();

    for (int i = tid; i < 1024; i += 512) {
        const int r = i >> 5, o = i & 31;
        float am = bm0[o], al = bl0[o];
#pragma unroll
        for (int j = 0; j < 8; ++j) {
            am += Pm[j * 1024 + r * 32 + o];
            al += Pl[j * 1024 + r * 32 + o];
        }
        x0[r][o] = fmaf(g, fmaxf(am, 0.0f), gi * al);
    }
    __syncthreads();

    if (tid < 32) {
        float s = 0.0f, s2 = 0.0f;
#pragma unroll
        for (int r = 0; r < 32; ++r) {
            const float v = x0[r][tid];
            s += v;
            s2 = fmaf(v, v, s2);
        }
        const float mu  = s * (1.0f / 32.0f);
        const float var = s2 * (1.0f / 32.0f) - mu * mu;
        const float m = bn_gamma[tid] * rsqrtf(var + 1e-5f);
        bnm[tid] = m;
        bna[tid] = fmaf(-mu, m, bn_beta[tid]);
    }
    __syncthreads();

    if (tid < 64) {
        const int b = tid >> 1, oo = tid & 1;
        float acc = bout[oo];
#pragma unroll
        for (int t = 0; t < 32; ++t) {
            const float xn = fmaf(x0[b][t], bnm[t], bna[t]);
            acc = fmaf(xn, Wout[oo * 32 + t], acc);
        }
        out[b * 2 + oo] = acc;
    }
}

extern "C" void kernel_launch(void* const* d_in, const int* in_sizes, int n_in,
                              void* d_out, int out_size, void* d_ws, size_t ws_size,
                              hipStream_t stream)
{
    const float* x    = (const float*)d_in[0];
    const float* Wm3  = (const float*)d_in[1];
    const float* bm3  = (const float*)d_in[2];
    const float* Wl3  = (const float*)d_in[3];
    const float* bl3  = (const float*)d_in[4];
    const float* Wm2  = (const float*)d_in[5];
    const float* bm2  = (const float*)d_in[6];
    const float* Wl2  = (const float*)d_in[7];
    const float* bl2  = (const float*)d_in[8];
    const float* Wm1  = (const float*)d_in[9];
    const float* bm1  = (const float*)d_in[10];
    const float* Wl1  = (const float*)d_in[11];
    const float* bl1  = (const float*)d_in[12];
    const float* Wm0  = (const float*)d_in[13];
    const float* bm0  = (const float*)d_in[14];
    const float* Wl0  = (const float*)d_in[15];
    const float* bl0  = (const float*)d_in[16];
    const float* gate = (const float*)d_in[17];
    const float* bn_g = (const float*)d_in[18];
    const float* bn_b = (const float*)d_in[19];
    const float* Wout = (const float*)d_in[20];
    const float* bout = (const float*)d_in[21];
    float* outp = (float*)d_out;

    float* ws  = (float*)d_ws;
    float* X2  = ws;               // 65536 floats
    float* XL2 = ws + 65536;       // 65536
    float* Pm  = ws + 131072;      // 8192
    float* Pl  = ws + 139264;      // 8192
    int*   cnt = (int*)(ws + 147456);

    hipLaunchKernelGGL(k_subtree, dim3(256), dim3(512), 0, stream,
                       x, Wm3, bm3, Wl3, bl3, Wm2, bm2, Wl2, bl2, gate,
                       X2, XL2, cnt);
    hipLaunchKernelGGL(k_l1tail, dim3(32), dim3(512), 0, stream,
                       X2, XL2, Wm1, bm1, Wl1, bl1, Wm0, bm0, Wl0, bl0,
                       gate, bn_g, bn_b, Wout, bout, Pm, Pl, cnt, outp);
}